// Round 7
// baseline (159.483 us; speedup 1.0000x reference)
//
#include <hip/hip_runtime.h>

// ===== ROUND 7: DECOMPOSITION PROBE =====
// Four dispatches, reps=16 each, decomposing V6's per-rep cost:
//   A MODE=0 STAGE_ONLY : staging + barriers only
//   B MODE=1 FAKEW      : full compute, weights = compile-time consts (no SMEM)
//   C MODE=2 NO_HALO    : real weights, halo zeroed (no shfl/bpermute)
//   D MODE=3 FULL       : exact V6 work, runs LAST -> validated output
// A/B/C write garbage to d_out; D overwrites with correct values.
// asm memory clobber per rep defeats cross-rep load CSE (rule #17).

#define N_ 8
#define C_ 16
#define H_ 32
#define W_ 32
#define O_ 64
#define F_ 144
#define HT 8
#define RT (HT + 2)      // 10 staged rows
#define RSTR 36          // row stride in words

template<int MODE>       // 0 stage-only, 1 fake-weights, 2 no-halo, 3 full
__global__ __launch_bounds__(256)
void normdist_probe(const float* __restrict__ x,
                    const float* __restrict__ weight,
                    const float* __restrict__ bias,
                    float* __restrict__ out,
                    int reps)
{
    __shared__ float xs[C_ * RT * RSTR];   // [c][r][36], bank-baseline
    __shared__ float sc[3][2][HT][W_];

    const int tid = threadIdx.x;
    const int o0  = blockIdx.x * 2;
    const int h0  = blockIdx.y * HT;
    const int n   = blockIdx.z;

    const float* __restrict__ xn = x + (size_t)n * (C_ * H_ * W_);
    const float* __restrict__ wr = weight + (size_t)o0 * F_;

    const int wq = tid & 7;
    const int hl = (tid >> 3) & 7;
    const int g  = tid >> 6;
    const int w0 = wq * 4;
    const bool left_edge  = (wq == 0);
    const bool right_edge = (wq == 7);
    const int cbase = __builtin_amdgcn_readfirstlane(g) * 4;

    float m[2][4];
    #pragma unroll
    for (int og = 0; og < 2; ++og)
        #pragma unroll
        for (int p = 0; p < 4; ++p)
            m[og][p] = 0.f;

    for (int rep = 0; rep < reps; ++rep) {
        // ---- staging: 1280 float4, 5 per thread ----
        #pragma unroll
        for (int k = 0; k < 5; ++k) {
            int idx  = tid + k * 256;
            int swq  = idx & 7;
            int c    = (idx >> 3) & 15;
            int r    = idx >> 7;
            int grow = h0 - 1 + r;
            float4 v = make_float4(0.f, 0.f, 0.f, 0.f);
            if (grow >= 0 && grow < H_)
                v = *reinterpret_cast<const float4*>(xn + c * (H_ * W_) + grow * W_ + swq * 4);
            *reinterpret_cast<float4*>(&xs[(c * RT + r) * RSTR + swq * 4]) = v;
        }
        __syncthreads();

        if (MODE != 0) {
            #pragma unroll
            for (int cc = 0; cc < 4; ++cc) {
                const int c = cbase + cc;
                #pragma unroll
                for (int kh = 0; kh < 3; ++kh) {
                    const int R = hl + kh;
                    float4 xm = *reinterpret_cast<const float4*>(
                        &xs[(c * RT + R) * RSTR + w0]);
                    float xl, xr;
                    if (MODE == 2) {           // no-halo ablation
                        xl = 0.f; xr = 0.f;
                    } else {
                        xl = __shfl_up(xm.w, 1);
                        xr = __shfl_down(xm.x, 1);
                        xl = left_edge  ? 0.f : xl;
                        xr = right_edge ? 0.f : xr;
                    }
                    float xw[6] = {xl, xm.x, xm.y, xm.z, xm.w, xr};
                    const int f = c * 9 + kh * 3;
                    #pragma unroll
                    for (int og = 0; og < 2; ++og) {
                        float wv0, wv1, wv2;
                        if (MODE == 1) {       // fake weights: no SMEM traffic
                            wv0 = (float)(og * F_ + f + 0) * 0.0078125f;
                            wv1 = (float)(og * F_ + f + 1) * 0.0078125f;
                            wv2 = (float)(og * F_ + f + 2) * 0.0078125f;
                        } else {
                            wv0 = wr[og * F_ + f + 0];
                            wv1 = wr[og * F_ + f + 1];
                            wv2 = wr[og * F_ + f + 2];
                        }
                        #pragma unroll
                        for (int p = 0; p < 4; ++p) {
                            float v0 = __builtin_fabsf(xw[p + 0] - wv0);
                            float v1 = __builtin_fabsf(xw[p + 1] - wv1);
                            float v2 = __builtin_fabsf(xw[p + 2] - wv2);
                            float mm = m[og][p];
                            mm = fmaxf(fmaxf(mm, v0), v1);
                            m[og][p] = fmaxf(mm, v2);
                        }
                    }
                }
            }
        }
        __syncthreads();
        asm volatile("" ::: "memory");   // no cross-rep CSE/hoist
    }

    // ---- publish + combine + store (once) ----
    if (g > 0) {
        #pragma unroll
        for (int og = 0; og < 2; ++og)
            *reinterpret_cast<float4*>(&sc[g - 1][og][hl][w0]) =
                make_float4(m[og][0], m[og][1], m[og][2], m[og][3]);
    }
    __syncthreads();

    if (g == 0) {
        #pragma unroll
        for (int og = 0; og < 2; ++og) {
            float4 a = *reinterpret_cast<const float4*>(&sc[0][og][hl][w0]);
            float4 b = *reinterpret_cast<const float4*>(&sc[1][og][hl][w0]);
            float4 d = *reinterpret_cast<const float4*>(&sc[2][og][hl][w0]);
            const float bv = bias[o0 + og];
            float4 r;
            r.x = fmaxf(fmaxf(fmaxf(m[og][0], a.x), b.x), d.x) + bv;
            r.y = fmaxf(fmaxf(fmaxf(m[og][1], a.y), b.y), d.y) + bv;
            r.z = fmaxf(fmaxf(fmaxf(m[og][2], a.z), b.z), d.z) + bv;
            r.w = fmaxf(fmaxf(fmaxf(m[og][3], a.w), b.w), d.w) + bv;
            float* dst = out + ((size_t)(n * O_ + o0 + og) * (H_ * W_))
                             + (h0 + hl) * W_ + w0;
            *reinterpret_cast<float4*>(dst) = r;
        }
    }
}

extern "C" void kernel_launch(void* const* d_in, const int* in_sizes, int n_in,
                              void* d_out, int out_size, void* d_ws, size_t ws_size,
                              hipStream_t stream) {
    const float* x  = (const float*)d_in[0];
    const float* w  = (const float*)d_in[1];
    const float* b  = (const float*)d_in[2];
    float* out      = (float*)d_out;

    dim3 grid(O_ / 2, H_ / HT, N_);   // 1024 blocks
    dim3 block(256);
    const int reps = 16;

    // A, B, C (garbage output), then D = correct, validated
    hipLaunchKernelGGL(normdist_probe<0>, grid, block, 0, stream, x, w, b, out, reps);
    hipLaunchKernelGGL(normdist_probe<1>, grid, block, 0, stream, x, w, b, out, reps);
    hipLaunchKernelGGL(normdist_probe<2>, grid, block, 0, stream, x, w, b, out, reps);
    hipLaunchKernelGGL(normdist_probe<3>, grid, block, 0, stream, x, w, b, out, reps);
}

// Round 8
// 12.727 us; speedup vs baseline: 12.5312x; 12.5312x over previous
//
#include <hip/hip_runtime.h>

// NormDistConv V8: out[n,o,h,w] = max_f |patch(n,:,h,w)[f] - weight[o,f]| + bias[o]
// x: (8,16,32,32) f32, weight: (64,144) f32, bias: (64,) f32, out: (8,64,32,32) f32
//
// Lane = output channel (64 lanes = 64 o). Wave task = (4 px, c-half).
//   - lane's 72 weights preloaded ONCE into 18 float4 VGPRs (L1/L2-hot global)
//   - x-patch values are wave-uniform -> LDS broadcast reads (1 b128 + 2 b32
//     per (c,kh), single base reg + compile-time offsets), halo pre-padded
//     into the tile: NO shfl / cndmask / edge logic in the hot loop
//   - c-halves combined via LDS partial max (pairs of waves)
// Grid 512 = (32 rows, 2 w-halves, 8 n) x 512 thr (8 waves: 4 px-quads x 2 ch).
// VGPR target <=128 -> __launch_bounds__(512,4): 16 waves/CU.

#define N_ 8
#define C_ 16
#define H_ 32
#define W_ 32
#define O_ 64
#define F_ 144

typedef __attribute__((ext_vector_type(4))) float f4;

__global__ __launch_bounds__(512, 4)
void normdist_kernel(const float* __restrict__ x,
                     const float* __restrict__ weight,
                     const float* __restrict__ bias,
                     float* __restrict__ out)
{
    __shared__ float xs[C_ * 3 * 24];     // [c][r][24], cols 3..20 = w-1..w+16
    __shared__ f4    sc[4][O_];           // c-half-1 partials per (quad, o)

    const int tid   = threadIdx.x;
    const int h     = blockIdx.x;
    const int wbase = blockIdx.y * 16;
    const int n     = blockIdx.z;

    const float* __restrict__ xn = x + (size_t)n * (C_ * H_ * W_);

    // ---- stage x tile: 16c x 3r x 18 cols, OOB -> 0 (pad baked in) ----
    for (int t = tid; t < C_ * 3 * 18; t += 512) {
        int wloc = t % 18;                 // 0..17 -> gw = wbase-1+wloc
        int r    = (t / 18) % 3;
        int c    = t / 54;
        int gw   = wbase - 1 + wloc;
        int gr   = h - 1 + r;
        float v = 0.f;
        if (gr >= 0 && gr < H_ && gw >= 0 && gw < W_)
            v = xn[c * (H_ * W_) + gr * W_ + gw];
        xs[(c * 3 + r) * 24 + 3 + wloc] = v;
    }

    const int lane = tid & 63;             // = output channel o
    const int wv64 = tid >> 6;             // wave id 0..7
    const int q    = wv64 & 3;             // pixel quad -> w0 = wbase + 4q
    const int ch   = wv64 >> 2;            // c-half 0/1

    // ---- preload this lane's 72 weights into VGPRs (once) ----
    f4 wv[18];
    const float* wrow = weight + (size_t)lane * F_ + ch * 72;
    #pragma unroll
    for (int t = 0; t < 18; ++t)
        wv[t] = *reinterpret_cast<const f4*>(wrow + 4 * t);

    __syncthreads();

    // ---- hot loop: 24 (c,kh), all x reads wave-uniform broadcasts ----
    const float* xq = xs + ch * (8 * 3 * 24) + 4 * q;  // single base per wave
    float m0 = 0.f, m1 = 0.f, m2 = 0.f, m3 = 0.f;

    #pragma unroll
    for (int cc = 0; cc < 8; ++cc) {
        #pragma unroll
        for (int kh = 0; kh < 3; ++kh) {
            const float* rp = xq + cc * 72 + kh * 24;
            float xw0 = rp[3];                              // ds b32 broadcast
            f4    xm  = *reinterpret_cast<const f4*>(rp + 4); // ds b128
            float xw5 = rp[8];                              // ds b32
            float xw1 = xm[0], xw2 = xm[1], xw3 = xm[2], xw4 = xm[3];
            const int j = cc * 9 + kh * 3;                  // compile-time
            float w0v = wv[(j + 0) >> 2][(j + 0) & 3];
            float w1v = wv[(j + 1) >> 2][(j + 1) & 3];
            float w2v = wv[(j + 2) >> 2][(j + 2) & 3];
            m0 = fmaxf(fmaxf(fmaxf(m0, __builtin_fabsf(xw0 - w0v)),
                             __builtin_fabsf(xw1 - w1v)),
                       __builtin_fabsf(xw2 - w2v));
            m1 = fmaxf(fmaxf(fmaxf(m1, __builtin_fabsf(xw1 - w0v)),
                             __builtin_fabsf(xw2 - w1v)),
                       __builtin_fabsf(xw3 - w2v));
            m2 = fmaxf(fmaxf(fmaxf(m2, __builtin_fabsf(xw2 - w0v)),
                             __builtin_fabsf(xw3 - w1v)),
                       __builtin_fabsf(xw4 - w2v));
            m3 = fmaxf(fmaxf(fmaxf(m3, __builtin_fabsf(xw3 - w0v)),
                             __builtin_fabsf(xw4 - w1v)),
                       __builtin_fabsf(xw5 - w2v));
        }
    }

    // ---- combine c-halves: ch1 publishes, ch0 reduces + bias + store ----
    if (ch == 1) {
        f4 v; v[0] = m0; v[1] = m1; v[2] = m2; v[3] = m3;
        sc[q][lane] = v;
    }
    __syncthreads();

    if (ch == 0) {
        f4 p = sc[q][lane];
        const float bv = bias[lane];
        f4 r;
        r[0] = fmaxf(m0, p[0]) + bv;
        r[1] = fmaxf(m1, p[1]) + bv;
        r[2] = fmaxf(m2, p[2]) + bv;
        r[3] = fmaxf(m3, p[3]) + bv;
        float* dst = out + ((size_t)(n * O_ + lane) * (H_ * W_))
                         + h * W_ + wbase + 4 * q;
        *reinterpret_cast<f4*>(dst) = r;
    }
}

extern "C" void kernel_launch(void* const* d_in, const int* in_sizes, int n_in,
                              void* d_out, int out_size, void* d_ws, size_t ws_size,
                              hipStream_t stream) {
    const float* x  = (const float*)d_in[0];
    const float* w  = (const float*)d_in[1];
    const float* b  = (const float*)d_in[2];
    float* out      = (float*)d_out;

    dim3 grid(H_, 2, N_);   // 32 rows x 2 w-halves x 8 n = 512 blocks
    dim3 block(512);
    hipLaunchKernelGGL(normdist_kernel, grid, block, 0, stream, x, w, b, out);
}

// Round 9
// 10.752 us; speedup vs baseline: 14.8332x; 1.1837x over previous
//
#include <hip/hip_runtime.h>

// NormDistConv V9: out[n,o,h,w] = max_f |patch(n,:,h,w)[f] - weight[o,f]| + bias[o]
// x: (8,16,32,32) f32, weight: (64,144) f32, bias: (64,) f32, out: (8,64,32,32) f32
//
// V9 = V6 structure with OG=4 (was 2): same x registers serve 4 output
// channels -> per-element overhead halves (kernel is VALU-issue-bound,
// probe r7: VALUBusy 81%, FAKEW==NO_HALO==FULL).
//   grid 512 = (16 og-groups, 4 h-tiles, 8 n), 256 thr (4 waves, wave=c-group)
//   LDS x-tile [c][r][36] (bank-baseline writes+reads), halo via shfl,
//   weights via s_load broadcast (probe-proven free), c-split partial-max.

#define N_ 8
#define C_ 16
#define H_ 32
#define W_ 32
#define O_ 64
#define F_ 144
#define OG 4
#define HT 8
#define RT (HT + 2)      // 10 staged rows
#define RSTR 36          // row stride in words

__global__ __launch_bounds__(256)
void normdist_kernel(const float* __restrict__ x,
                     const float* __restrict__ weight,
                     const float* __restrict__ bias,
                     float* __restrict__ out)
{
    __shared__ float xs[C_ * RT * RSTR];   // 23 KB, [c][r][36]
    __shared__ float sc[3][OG][HT][W_];    // 12 KB partial maxes

    const int tid = threadIdx.x;
    const int o0  = blockIdx.x * OG;
    const int h0  = blockIdx.y * HT;
    const int n   = blockIdx.z;

    const float* __restrict__ xn = x + (size_t)n * (C_ * H_ * W_);
    const float* __restrict__ wr = weight + (size_t)o0 * F_;

    // ---- stage 16 ch x 10 rows x 32 w: 1280 float4, 5 per thread ----
    #pragma unroll
    for (int k = 0; k < 5; ++k) {
        int idx  = tid + k * 256;
        int swq  = idx & 7;
        int c    = (idx >> 3) & 15;
        int r    = idx >> 7;               // 0..9
        int grow = h0 - 1 + r;
        float4 v = make_float4(0.f, 0.f, 0.f, 0.f);
        if (grow >= 0 && grow < H_)
            v = *reinterpret_cast<const float4*>(xn + c * (H_ * W_) + grow * W_ + swq * 4);
        *reinterpret_cast<float4*>(&xs[(c * RT + r) * RSTR + swq * 4]) = v;
    }
    __syncthreads();

    const int wq = tid & 7;                // w-quad
    const int hl = (tid >> 3) & 7;         // output row in tile
    const int g  = tid >> 6;               // wave id = c-group
    const int w0 = wq * 4;
    const bool left_edge  = (wq == 0);
    const bool right_edge = (wq == 7);

    const int cbase = __builtin_amdgcn_readfirstlane(g) * 4;  // SGPR-uniform

    float m[OG][4];
    #pragma unroll
    for (int og = 0; og < OG; ++og)
        #pragma unroll
        for (int p = 0; p < 4; ++p)
            m[og][p] = 0.f;                // |x-w| >= 0: safe identity

    #pragma unroll
    for (int cc = 0; cc < 4; ++cc) {
        const int c = cbase + cc;
        #pragma unroll
        for (int kh = 0; kh < 3; ++kh) {
            const int R = hl + kh;         // staged row 0..9
            float4 xm = *reinterpret_cast<const float4*>(&xs[(c * RT + R) * RSTR + w0]);
            // halo from neighbor lane (same hl row); clamped/cross lanes are
            // exactly the edge lanes masked to the 0-pad value.
            float xl = __shfl_up(xm.w, 1);
            float xr = __shfl_down(xm.x, 1);
            xl = left_edge  ? 0.f : xl;
            xr = right_edge ? 0.f : xr;
            const float xw0 = xl,   xw1 = xm.x, xw2 = xm.y;
            const float xw3 = xm.z, xw4 = xm.w, xw5 = xr;
            const int f = c * 9 + kh * 3;
            #pragma unroll
            for (int og = 0; og < OG; ++og) {
                const float wv0 = wr[og * F_ + f + 0];
                const float wv1 = wr[og * F_ + f + 1];
                const float wv2 = wr[og * F_ + f + 2];
                float m0 = m[og][0], m1 = m[og][1];
                float m2 = m[og][2], m3 = m[og][3];
                m0 = fmaxf(fmaxf(fmaxf(m0, __builtin_fabsf(xw0 - wv0)),
                                 __builtin_fabsf(xw1 - wv1)),
                           __builtin_fabsf(xw2 - wv2));
                m1 = fmaxf(fmaxf(fmaxf(m1, __builtin_fabsf(xw1 - wv0)),
                                 __builtin_fabsf(xw2 - wv1)),
                           __builtin_fabsf(xw3 - wv2));
                m2 = fmaxf(fmaxf(fmaxf(m2, __builtin_fabsf(xw2 - wv0)),
                                 __builtin_fabsf(xw3 - wv1)),
                           __builtin_fabsf(xw4 - wv2));
                m3 = fmaxf(fmaxf(fmaxf(m3, __builtin_fabsf(xw3 - wv0)),
                                 __builtin_fabsf(xw4 - wv1)),
                           __builtin_fabsf(xw5 - wv2));
                m[og][0] = m0; m[og][1] = m1;
                m[og][2] = m2; m[og][3] = m3;
            }
        }
    }

    // ---- c-split combine: groups 1..3 publish, wave 0 reduces + stores ----
    if (g > 0) {
        #pragma unroll
        for (int og = 0; og < OG; ++og)
            *reinterpret_cast<float4*>(&sc[g - 1][og][hl][w0]) =
                make_float4(m[og][0], m[og][1], m[og][2], m[og][3]);
    }
    __syncthreads();

    if (g == 0) {
        #pragma unroll
        for (int og = 0; og < OG; ++og) {
            float4 a = *reinterpret_cast<const float4*>(&sc[0][og][hl][w0]);
            float4 b = *reinterpret_cast<const float4*>(&sc[1][og][hl][w0]);
            float4 d = *reinterpret_cast<const float4*>(&sc[2][og][hl][w0]);
            const float bv = bias[o0 + og];
            float4 r;
            r.x = fmaxf(fmaxf(fmaxf(m[og][0], a.x), b.x), d.x) + bv;
            r.y = fmaxf(fmaxf(fmaxf(m[og][1], a.y), b.y), d.y) + bv;
            r.z = fmaxf(fmaxf(fmaxf(m[og][2], a.z), b.z), d.z) + bv;
            r.w = fmaxf(fmaxf(fmaxf(m[og][3], a.w), b.w), d.w) + bv;
            float* dst = out + ((size_t)(n * O_ + o0 + og) * (H_ * W_))
                             + (h0 + hl) * W_ + w0;
            *reinterpret_cast<float4*>(dst) = r;
        }
    }
}

extern "C" void kernel_launch(void* const* d_in, const int* in_sizes, int n_in,
                              void* d_out, int out_size, void* d_ws, size_t ws_size,
                              hipStream_t stream) {
    const float* x  = (const float*)d_in[0];
    const float* w  = (const float*)d_in[1];
    const float* b  = (const float*)d_in[2];
    float* out      = (float*)d_out;

    dim3 grid(O_ / OG, H_ / HT, N_);   // 16 x 4 x 8 = 512 blocks
    dim3 block(256);
    hipLaunchKernelGGL(normdist_kernel, grid, block, 0, stream, x, w, b, out);
}

// Round 10
// 10.367 us; speedup vs baseline: 15.3839x; 1.0371x over previous
//
#include <hip/hip_runtime.h>

// NormDistConv V10: out[n,o,h,w] = max_f |patch(n,:,h,w)[f] - weight[o,f]| + bias[o]
// x: (8,16,32,32) f32, weight: (64,144) f32, bias: (64,) f32, out: (8,64,32,32) f32
//
// V10 = V9 (OG=4, low VALU count) + 8 waves/block (c-split x8, 2 ch/wave):
// 512 blocks x 512 thr -> 16 waves/CU = 4/SIMD (V9 had 2/SIMD; r7 probe showed
// issue efficiency ~81% needs >=4 waves/SIMD). Total lane-ops ~150M -> steady
// VALU ~2.4us; K_pred 3.6-4.3; dur_pred 9.3-10.0 (O~5.7 fixed, reps-fit).
//   LDS x-tile [c][r][36] bank-baseline; halo via shfl; s_load weights;
//   8-way c-split partial-max combine (waves 1..7 publish, wave 0 folds).

#define N_ 8
#define C_ 16
#define H_ 32
#define W_ 32
#define O_ 64
#define F_ 144
#define OG 4
#define HT 8
#define RT (HT + 2)      // 10 staged rows
#define RSTR 36          // row stride in words

__global__ __launch_bounds__(512, 4)
void normdist_kernel(const float* __restrict__ x,
                     const float* __restrict__ weight,
                     const float* __restrict__ bias,
                     float* __restrict__ out)
{
    __shared__ float xs[C_ * RT * RSTR];     // 23 KB, [c][r][36]
    __shared__ float sc[7][OG][HT][W_];      // 28 KB partial maxes (waves 1..7)

    const int tid = threadIdx.x;
    const int o0  = blockIdx.x * OG;
    const int h0  = blockIdx.y * HT;
    const int n   = blockIdx.z;

    const float* __restrict__ xn = x + (size_t)n * (C_ * H_ * W_);
    const float* __restrict__ wr = weight + (size_t)o0 * F_;

    // ---- stage 16 ch x 10 rows x 32 w: 1280 float4, <=3 per thread ----
    #pragma unroll
    for (int k = 0; k < 3; ++k) {
        int idx = tid + k * 512;
        if (idx < 1280) {
            int swq  = idx & 7;
            int c    = (idx >> 3) & 15;
            int r    = idx >> 7;               // 0..9
            int grow = h0 - 1 + r;
            float4 v = make_float4(0.f, 0.f, 0.f, 0.f);
            if (grow >= 0 && grow < H_)
                v = *reinterpret_cast<const float4*>(xn + c * (H_ * W_) + grow * W_ + swq * 4);
            *reinterpret_cast<float4*>(&xs[(c * RT + r) * RSTR + swq * 4]) = v;
        }
    }
    __syncthreads();

    const int lane = tid & 63;
    const int wq = lane & 7;               // w-quad
    const int hl = lane >> 3;              // output row in tile (0..7)
    const int g  = tid >> 6;               // wave id = c-group (0..7)
    const int w0 = wq * 4;
    const bool left_edge  = (wq == 0);
    const bool right_edge = (wq == 7);

    const int cbase = __builtin_amdgcn_readfirstlane(g) * 2;  // SGPR-uniform

    float m[OG][4];
    #pragma unroll
    for (int og = 0; og < OG; ++og)
        #pragma unroll
        for (int p = 0; p < 4; ++p)
            m[og][p] = 0.f;                 // |x-w| >= 0: safe identity

    #pragma unroll
    for (int cc = 0; cc < 2; ++cc) {        // 2 channels per wave
        const int c = cbase + cc;
        #pragma unroll
        for (int kh = 0; kh < 3; ++kh) {
            const int R = hl + kh;          // staged row 0..9
            float4 xm = *reinterpret_cast<const float4*>(&xs[(c * RT + R) * RSTR + w0]);
            // halo from neighbor lane (same hl row); clamped/cross-row lanes
            // are exactly the edge lanes masked to the 0-pad value.
            float xl = __shfl_up(xm.w, 1);
            float xr = __shfl_down(xm.x, 1);
            xl = left_edge  ? 0.f : xl;
            xr = right_edge ? 0.f : xr;
            const float xw0 = xl,   xw1 = xm.x, xw2 = xm.y;
            const float xw3 = xm.z, xw4 = xm.w, xw5 = xr;
            const int f = c * 9 + kh * 3;
            #pragma unroll
            for (int og = 0; og < OG; ++og) {
                const float wv0 = wr[og * F_ + f + 0];
                const float wv1 = wr[og * F_ + f + 1];
                const float wv2 = wr[og * F_ + f + 2];
                float m0 = m[og][0], m1 = m[og][1];
                float m2 = m[og][2], m3 = m[og][3];
                m0 = fmaxf(fmaxf(fmaxf(m0, __builtin_fabsf(xw0 - wv0)),
                                 __builtin_fabsf(xw1 - wv1)),
                           __builtin_fabsf(xw2 - wv2));
                m1 = fmaxf(fmaxf(fmaxf(m1, __builtin_fabsf(xw1 - wv0)),
                                 __builtin_fabsf(xw2 - wv1)),
                           __builtin_fabsf(xw3 - wv2));
                m2 = fmaxf(fmaxf(fmaxf(m2, __builtin_fabsf(xw2 - wv0)),
                                 __builtin_fabsf(xw3 - wv1)),
                           __builtin_fabsf(xw4 - wv2));
                m3 = fmaxf(fmaxf(fmaxf(m3, __builtin_fabsf(xw3 - wv0)),
                                 __builtin_fabsf(xw4 - wv1)),
                           __builtin_fabsf(xw5 - wv2));
                m[og][0] = m0; m[og][1] = m1;
                m[og][2] = m2; m[og][3] = m3;
            }
        }
    }

    // ---- c-split combine: waves 1..7 publish, wave 0 folds + stores ----
    if (g > 0) {
        #pragma unroll
        for (int og = 0; og < OG; ++og)
            *reinterpret_cast<float4*>(&sc[g - 1][og][hl][w0]) =
                make_float4(m[og][0], m[og][1], m[og][2], m[og][3]);
    }
    __syncthreads();

    if (g == 0) {
        #pragma unroll
        for (int og = 0; og < OG; ++og) {
            float p0 = m[og][0], p1 = m[og][1], p2 = m[og][2], p3 = m[og][3];
            #pragma unroll
            for (int j = 0; j < 7; ++j) {
                float4 a = *reinterpret_cast<const float4*>(&sc[j][og][hl][w0]);
                p0 = fmaxf(p0, a.x); p1 = fmaxf(p1, a.y);
                p2 = fmaxf(p2, a.z); p3 = fmaxf(p3, a.w);
            }
            const float bv = bias[o0 + og];
            float* dst = out + ((size_t)(n * O_ + o0 + og) * (H_ * W_))
                             + (h0 + hl) * W_ + w0;
            *reinterpret_cast<float4*>(dst) =
                make_float4(p0 + bv, p1 + bv, p2 + bv, p3 + bv);
        }
    }
}

extern "C" void kernel_launch(void* const* d_in, const int* in_sizes, int n_in,
                              void* d_out, int out_size, void* d_ws, size_t ws_size,
                              hipStream_t stream) {
    const float* x  = (const float*)d_in[0];
    const float* w  = (const float*)d_in[1];
    const float* b  = (const float*)d_in[2];
    float* out      = (float*)d_out;

    dim3 grid(O_ / OG, H_ / HT, N_);   // 16 x 4 x 8 = 512 blocks
    dim3 block(512);
    hipLaunchKernelGGL(normdist_kernel, grid, block, 0, stream, x, w, b, out);
}

// Round 11
// 10.191 us; speedup vs baseline: 15.6497x; 1.0173x over previous
//
#include <hip/hip_runtime.h>

// NormDistConv V11: out[n,o,h,w] = max_f |patch(n,:,h,w)[f] - weight[o,f]| + bias[o]
// x: (8,16,32,32) f32, weight: (64,144) f32, bias: (64,) f32, out: (8,64,32,32) f32
//
// V11 = V10 minus the x-staging pass-through: c-split gives zero intra-block
// x reuse, so LDS staging was pure overhead (instr + stage barrier + lgkm
// coupling with s_load weights). x now read direct from global (L1/L2-hot,
// vmcnt) -- stage barrier gone, waves compute immediately at launch.
// Vertical pad: interior blocks (h0=8,16) have no edge code (uniform branch);
// edge blocks clamp row addr + cndmask values (halo lanes inherit zeros via shfl).
//   grid 512 = (16 og-groups, 4 h-tiles, 8 n) x 512 thr (8 waves, wave=c-pair)
//   weights via s_load broadcast; 8-way c-split partial-max combine in LDS.

#define N_ 8
#define C_ 16
#define H_ 32
#define W_ 32
#define O_ 64
#define F_ 144
#define OG 4
#define HT 8

template<bool EDGE>
__device__ __forceinline__ void hot_loop(const float* __restrict__ xroot,
                                         const float* __restrict__ wr,
                                         int cbase, int h0, int hl,
                                         bool left_edge, bool right_edge,
                                         float (&m)[OG][4])
{
    #pragma unroll
    for (int cc = 0; cc < 2; ++cc) {        // 2 channels per wave (c-split x8)
        const int c = cbase + cc;
        const float* xc = xroot + c * (H_ * W_);
        #pragma unroll
        for (int kh = 0; kh < 3; ++kh) {
            const int grow = h0 - 1 + hl + kh;
            float4 xm;
            if constexpr (EDGE) {
                int growc = grow < 0 ? 0 : (grow > 31 ? 31 : grow);
                xm = *reinterpret_cast<const float4*>(xc + growc * W_);
                if (grow != growc)          // pad row -> zeros (4 cndmask)
                    xm = make_float4(0.f, 0.f, 0.f, 0.f);
            } else {
                xm = *reinterpret_cast<const float4*>(xc + grow * W_);
            }
            // horizontal halo from neighbor lane (same hl row). Zeroed pad
            // values propagate through the shfl; clamped/cross-row lanes are
            // exactly the edge lanes masked to the 0-pad value.
            float xl = __shfl_up(xm.w, 1);
            float xr = __shfl_down(xm.x, 1);
            xl = left_edge  ? 0.f : xl;
            xr = right_edge ? 0.f : xr;
            const float xw0 = xl,   xw1 = xm.x, xw2 = xm.y;
            const float xw3 = xm.z, xw4 = xm.w, xw5 = xr;
            const int f = c * 9 + kh * 3;
            #pragma unroll
            for (int og = 0; og < OG; ++og) {
                const float wv0 = wr[og * F_ + f + 0];   // s_load broadcast
                const float wv1 = wr[og * F_ + f + 1];
                const float wv2 = wr[og * F_ + f + 2];
                float m0 = m[og][0], m1 = m[og][1];
                float m2 = m[og][2], m3 = m[og][3];
                m0 = fmaxf(fmaxf(fmaxf(m0, __builtin_fabsf(xw0 - wv0)),
                                 __builtin_fabsf(xw1 - wv1)),
                           __builtin_fabsf(xw2 - wv2));
                m1 = fmaxf(fmaxf(fmaxf(m1, __builtin_fabsf(xw1 - wv0)),
                                 __builtin_fabsf(xw2 - wv1)),
                           __builtin_fabsf(xw3 - wv2));
                m2 = fmaxf(fmaxf(fmaxf(m2, __builtin_fabsf(xw2 - wv0)),
                                 __builtin_fabsf(xw3 - wv1)),
                           __builtin_fabsf(xw4 - wv2));
                m3 = fmaxf(fmaxf(fmaxf(m3, __builtin_fabsf(xw3 - wv0)),
                                 __builtin_fabsf(xw4 - wv1)),
                           __builtin_fabsf(xw5 - wv2));
                m[og][0] = m0; m[og][1] = m1;
                m[og][2] = m2; m[og][3] = m3;
            }
        }
    }
}

__global__ __launch_bounds__(512, 4)
void normdist_kernel(const float* __restrict__ x,
                     const float* __restrict__ weight,
                     const float* __restrict__ bias,
                     float* __restrict__ out)
{
    __shared__ float sc[7][OG][HT][W_];      // 28 KB partial maxes (waves 1..7)

    const int tid = threadIdx.x;
    const int o0  = blockIdx.x * OG;
    const int h0  = blockIdx.y * HT;
    const int n   = blockIdx.z;

    const int lane = tid & 63;
    const int wq = lane & 7;                 // w-quad
    const int hl = lane >> 3;                // output row in tile (0..7)
    const int g  = tid >> 6;                 // wave id = c-group (0..7)
    const int w0 = wq * 4;
    const bool left_edge  = (wq == 0);
    const bool right_edge = (wq == 7);

    const int cbase = __builtin_amdgcn_readfirstlane(g) * 2;   // SGPR-uniform
    const float* __restrict__ xroot = x + (size_t)n * (C_ * H_ * W_) + w0;
    const float* __restrict__ wr    = weight + (size_t)o0 * F_;

    float m[OG][4];
    #pragma unroll
    for (int og = 0; og < OG; ++og)
        #pragma unroll
        for (int p = 0; p < 4; ++p)
            m[og][p] = 0.f;                  // |x-w| >= 0: safe identity

    if (h0 == 0 || h0 + HT == H_)
        hot_loop<true >(xroot, wr, cbase, h0, hl, left_edge, right_edge, m);
    else
        hot_loop<false>(xroot, wr, cbase, h0, hl, left_edge, right_edge, m);

    // ---- c-split combine: waves 1..7 publish, wave 0 folds + stores ----
    if (g > 0) {
        #pragma unroll
        for (int og = 0; og < OG; ++og)
            *reinterpret_cast<float4*>(&sc[g - 1][og][hl][w0]) =
                make_float4(m[og][0], m[og][1], m[og][2], m[og][3]);
    }
    __syncthreads();

    if (g == 0) {
        #pragma unroll
        for (int og = 0; og < OG; ++og) {
            float p0 = m[og][0], p1 = m[og][1], p2 = m[og][2], p3 = m[og][3];
            #pragma unroll
            for (int j = 0; j < 7; ++j) {
                float4 a = *reinterpret_cast<const float4*>(&sc[j][og][hl][w0]);
                p0 = fmaxf(p0, a.x); p1 = fmaxf(p1, a.y);
                p2 = fmaxf(p2, a.z); p3 = fmaxf(p3, a.w);
            }
            const float bv = bias[o0 + og];
            float* dst = out + ((size_t)(n * O_ + o0 + og) * (H_ * W_))
                             + (h0 + hl) * W_ + w0;
            *reinterpret_cast<float4*>(dst) =
                make_float4(p0 + bv, p1 + bv, p2 + bv, p3 + bv);
        }
    }
}

extern "C" void kernel_launch(void* const* d_in, const int* in_sizes, int n_in,
                              void* d_out, int out_size, void* d_ws, size_t ws_size,
                              hipStream_t stream) {
    const float* x  = (const float*)d_in[0];
    const float* w  = (const float*)d_in[1];
    const float* b  = (const float*)d_in[2];
    float* out      = (float*)d_out;

    dim3 grid(O_ / OG, H_ / HT, N_);   // 16 x 4 x 8 = 512 blocks
    dim3 block(512);
    hipLaunchKernelGGL(normdist_kernel, grid, block, 0, stream, x, w, b, out);
}

// Round 12
// 10.023 us; speedup vs baseline: 15.9115x; 1.0167x over previous
//
#include <hip/hip_runtime.h>

// NormDistConv V12: out[n,o,h,w] = max_f |patch(n,:,h,w)[f] - weight[o,f]| + bias[o]
// x: (8,16,32,32) f32, weight: (64,144) f32, bias: (64,) f32, out: (8,64,32,32) f32
//
// V12 = V11 + distributed epilogue: all 8 waves publish partials; waves 0..3
// each fold ONE og in parallel (8 LDS reads + 1 store per lane) instead of
// wave 0 folding all four (28 reads + 4 stores) while 7 waves idle.
// Rule #20 care: runtime og=g only feeds LDS/global ADDRESS math, never a
// register-array index (all 8 partials re-read from LDS, m[] untouched).
//   x direct from global (L1/L2-hot, vmcnt path; no stage barrier);
//   weights via s_load broadcast; grid 512 x 512 thr = 4 waves/SIMD.

#define N_ 8
#define C_ 16
#define H_ 32
#define W_ 32
#define O_ 64
#define F_ 144
#define OG 4
#define HT 8

template<bool EDGE>
__device__ __forceinline__ void hot_loop(const float* __restrict__ xroot,
                                         const float* __restrict__ wr,
                                         int cbase, int h0, int hl,
                                         bool left_edge, bool right_edge,
                                         float (&m)[OG][4])
{
    #pragma unroll
    for (int cc = 0; cc < 2; ++cc) {        // 2 channels per wave (c-split x8)
        const int c = cbase + cc;
        const float* xc = xroot + c * (H_ * W_);
        #pragma unroll
        for (int kh = 0; kh < 3; ++kh) {
            const int grow = h0 - 1 + hl + kh;
            float4 xm;
            if constexpr (EDGE) {
                int growc = grow < 0 ? 0 : (grow > 31 ? 31 : grow);
                xm = *reinterpret_cast<const float4*>(xc + growc * W_);
                if (grow != growc)          // pad row -> zeros (4 cndmask)
                    xm = make_float4(0.f, 0.f, 0.f, 0.f);
            } else {
                xm = *reinterpret_cast<const float4*>(xc + grow * W_);
            }
            // horizontal halo from neighbor lane (same hl row); clamped /
            // cross-row lanes are exactly the edge lanes masked to 0-pad.
            float xl = __shfl_up(xm.w, 1);
            float xr = __shfl_down(xm.x, 1);
            xl = left_edge  ? 0.f : xl;
            xr = right_edge ? 0.f : xr;
            const float xw0 = xl,   xw1 = xm.x, xw2 = xm.y;
            const float xw3 = xm.z, xw4 = xm.w, xw5 = xr;
            const int f = c * 9 + kh * 3;
            #pragma unroll
            for (int og = 0; og < OG; ++og) {
                const float wv0 = wr[og * F_ + f + 0];   // s_load broadcast
                const float wv1 = wr[og * F_ + f + 1];
                const float wv2 = wr[og * F_ + f + 2];
                float m0 = m[og][0], m1 = m[og][1];
                float m2 = m[og][2], m3 = m[og][3];
                m0 = fmaxf(fmaxf(fmaxf(m0, __builtin_fabsf(xw0 - wv0)),
                                 __builtin_fabsf(xw1 - wv1)),
                           __builtin_fabsf(xw2 - wv2));
                m1 = fmaxf(fmaxf(fmaxf(m1, __builtin_fabsf(xw1 - wv0)),
                                 __builtin_fabsf(xw2 - wv1)),
                           __builtin_fabsf(xw3 - wv2));
                m2 = fmaxf(fmaxf(fmaxf(m2, __builtin_fabsf(xw2 - wv0)),
                                 __builtin_fabsf(xw3 - wv1)),
                           __builtin_fabsf(xw4 - wv2));
                m3 = fmaxf(fmaxf(fmaxf(m3, __builtin_fabsf(xw3 - wv0)),
                                 __builtin_fabsf(xw4 - wv1)),
                           __builtin_fabsf(xw5 - wv2));
                m[og][0] = m0; m[og][1] = m1;
                m[og][2] = m2; m[og][3] = m3;
            }
        }
    }
}

__global__ __launch_bounds__(512, 4)
void normdist_kernel(const float* __restrict__ x,
                     const float* __restrict__ weight,
                     const float* __restrict__ bias,
                     float* __restrict__ out)
{
    __shared__ float sc[8][OG][HT][W_];      // 32 KB: all 8 waves' partials

    const int tid = threadIdx.x;
    const int o0  = blockIdx.x * OG;
    const int h0  = blockIdx.y * HT;
    const int n   = blockIdx.z;

    const int lane = tid & 63;
    const int wq = lane & 7;                 // w-quad
    const int hl = lane >> 3;                // output row in tile (0..7)
    const int g  = tid >> 6;                 // wave id = c-group (0..7)
    const int w0 = wq * 4;
    const bool left_edge  = (wq == 0);
    const bool right_edge = (wq == 7);

    const int cbase = __builtin_amdgcn_readfirstlane(g) * 2;   // SGPR-uniform
    const float* __restrict__ xroot = x + (size_t)n * (C_ * H_ * W_) + w0;
    const float* __restrict__ wr    = weight + (size_t)o0 * F_;

    float m[OG][4];
    #pragma unroll
    for (int og = 0; og < OG; ++og)
        #pragma unroll
        for (int p = 0; p < 4; ++p)
            m[og][p] = 0.f;                  // |x-w| >= 0: safe identity

    if (h0 == 0 || h0 + HT == H_)
        hot_loop<true >(xroot, wr, cbase, h0, hl, left_edge, right_edge, m);
    else
        hot_loop<false>(xroot, wr, cbase, h0, hl, left_edge, right_edge, m);

    // ---- publish: every wave writes its 4 partial float4s (static og idx) ----
    #pragma unroll
    for (int og = 0; og < OG; ++og)
        *reinterpret_cast<float4*>(&sc[g][og][hl][w0]) =
            make_float4(m[og][0], m[og][1], m[og][2], m[og][3]);
    __syncthreads();

    // ---- distributed fold: wave g<4 owns output channel og = g ----
    if (g < OG) {
        const int og = g;                    // wave-uniform; ADDRESS use only
        float4 a = *reinterpret_cast<const float4*>(&sc[0][og][hl][w0]);
        float p0 = a.x, p1 = a.y, p2 = a.z, p3 = a.w;
        #pragma unroll
        for (int j = 1; j < 8; ++j) {
            float4 v = *reinterpret_cast<const float4*>(&sc[j][og][hl][w0]);
            p0 = fmaxf(p0, v.x); p1 = fmaxf(p1, v.y);
            p2 = fmaxf(p2, v.z); p3 = fmaxf(p3, v.w);
        }
        const float bv = bias[o0 + og];
        float* dst = out + ((size_t)(n * O_ + o0 + og) * (H_ * W_))
                         + (h0 + hl) * W_ + w0;
        *reinterpret_cast<float4*>(dst) =
            make_float4(p0 + bv, p1 + bv, p2 + bv, p3 + bv);
    }
}

extern "C" void kernel_launch(void* const* d_in, const int* in_sizes, int n_in,
                              void* d_out, int out_size, void* d_ws, size_t ws_size,
                              hipStream_t stream) {
    const float* x  = (const float*)d_in[0];
    const float* w  = (const float*)d_in[1];
    const float* b  = (const float*)d_in[2];
    float* out      = (float*)d_out;

    dim3 grid(O_ / OG, H_ / HT, N_);   // 16 x 4 x 8 = 512 blocks
    dim3 block(512);
    hipLaunchKernelGGL(normdist_kernel, grid, block, 0, stream, x, w, b, out);
}